// Round 1
// baseline (7025.924 us; speedup 1.0000x reference)
//
#include <hip/hip_runtime.h>
#include <hip/hip_bf16.h>
#include <math.h>

#define NF   128
#define HID  6
#define NC   10
#define NG   64

// ---------------- degree ----------------
__global__ void count_deg_kernel(const int* __restrict__ dst, float* __restrict__ deg, int E) {
    int e = blockIdx.x * blockDim.x + threadIdx.x;
    if (e >= E) return;
    atomicAdd(&deg[dst[e]], 1.0f);
}

__global__ void dinv_kernel(float* __restrict__ deg, int N) {
    int i = blockIdx.x * blockDim.x + threadIdx.x;
    if (i >= N) return;
    // +1 for the self loop
    deg[i] = rsqrtf(deg[i] + 1.0f);
}

// ---------------- layer 1: g = dinv * (x @ W1), one wave per node ----------------
__global__ void layer1_kernel(const float* __restrict__ x, const float* __restrict__ W,
                              const float* __restrict__ dinv, float* __restrict__ g, int N) {
    __shared__ float sW[NF * HID];
    for (int k = threadIdx.x; k < NF * HID; k += blockDim.x) sW[k] = W[k];
    __syncthreads();
    int wave = threadIdx.x >> 6;
    int lane = threadIdx.x & 63;
    int node = blockIdx.x * (blockDim.x >> 6) + wave;
    if (node >= N) return;
    float x0 = x[(size_t)node * NF + lane];
    float x1 = x[(size_t)node * NF + 64 + lane];
    float p[HID];
#pragma unroll
    for (int f = 0; f < HID; ++f)
        p[f] = x0 * sW[lane * HID + f] + x1 * sW[(lane + 64) * HID + f];
#pragma unroll
    for (int off = 32; off > 0; off >>= 1) {
#pragma unroll
        for (int f = 0; f < HID; ++f) p[f] += __shfl_down(p[f], off);
    }
    if (lane == 0) {
        float dv = dinv[node];
#pragma unroll
        for (int f = 0; f < HID; ++f) g[node * HID + f] = dv * p[f];
    }
}

// ---------------- edge scatter: acc[dst] += g[src], 6 floats ----------------
__global__ void scatter6_kernel(const int* __restrict__ src, const int* __restrict__ dst,
                                const float* __restrict__ g, float* __restrict__ acc, int E) {
    int e = blockIdx.x * blockDim.x + threadIdx.x;
    if (e >= E) return;
    int s = src[e];
    int d = dst[e];
    const float* gr = g + s * HID;
    float* ar = acc + d * HID;
#pragma unroll
    for (int f = 0; f < HID; ++f) atomicAdd(&ar[f], gr[f]);
}

// ---------------- mid layer epilogue fused with next matmul ----------------
// h = relu(dinv*(acc+g) + b_cur); g_next = dinv*(h @ W_next); acc re-zeroed.
__global__ void mid_kernel(const float* __restrict__ dinv, float* __restrict__ g,
                           float* __restrict__ acc, const float* __restrict__ Wn,
                           const float* __restrict__ bc, int N) {
    int i = blockIdx.x * blockDim.x + threadIdx.x;
    if (i >= N) return;
    float dv = dinv[i];
    int o = i * HID;
    float h[HID];
#pragma unroll
    for (int f = 0; f < HID; ++f) {
        float u = dv * (acc[o + f] + g[o + f]) + bc[f];
        h[f] = u > 0.0f ? u : 0.0f;
        acc[o + f] = 0.0f;
    }
#pragma unroll
    for (int fo = 0; fo < HID; ++fo) {
        float s = 0.0f;
#pragma unroll
        for (int fi = 0; fi < HID; ++fi) s += h[fi] * Wn[fi * HID + fo];
        g[o + fo] = dv * s;
    }
}

// ---------------- layer-6 epilogue (no next W; produce g7 = dinv*h6) ----------------
__global__ void prep7_kernel(const float* __restrict__ dinv, float* __restrict__ g,
                             float* __restrict__ acc, const float* __restrict__ bc, int N) {
    int i = blockIdx.x * blockDim.x + threadIdx.x;
    if (i >= N) return;
    float dv = dinv[i];
    int o = i * HID;
#pragma unroll
    for (int f = 0; f < HID; ++f) {
        float u = dv * (acc[o + f] + g[o + f]) + bc[f];
        u = u > 0.0f ? u : 0.0f;
        g[o + f] = dv * u;
        acc[o + f] = 0.0f;
    }
}

// ---------------- pool: per node, finish conv7 (agg6 @ Wf + bf, relu), LDS-reduce ----------------
__global__ void pool_kernel(const float* __restrict__ g, const float* __restrict__ acc,
                            const float* __restrict__ dinv, const int* __restrict__ batch,
                            const float* __restrict__ Wf, const float* __restrict__ bf,
                            float* __restrict__ pooled, float* __restrict__ cnt, int N) {
    __shared__ float sp[NG * NC];
    __shared__ float sc[NG];
    __shared__ int srange[2];
    for (int k = threadIdx.x; k < NG * NC; k += blockDim.x) sp[k] = 0.0f;
    if (threadIdx.x < NG) sc[threadIdx.x] = 0.0f;
    int start = blockIdx.x * blockDim.x;
    int endi = min(start + (int)blockDim.x, N) - 1;
    if (threadIdx.x == 0) {
        srange[0] = batch[start];   // batch is sorted
        srange[1] = batch[endi];
    }
    __syncthreads();
    int i = start + threadIdx.x;
    if (i < N) {
        float dv = dinv[i];
        int o = i * HID;
        float u[HID];
#pragma unroll
        for (int f = 0; f < HID; ++f) u[f] = dv * (acc[o + f] + g[o + f]);
        int bg = batch[i];
#pragma unroll
        for (int c = 0; c < NC; ++c) {
            float v = bf[c];
#pragma unroll
            for (int f = 0; f < HID; ++f) v += u[f] * Wf[f * NC + c];
            v = v > 0.0f ? v : 0.0f;
            atomicAdd(&sp[bg * NC + c], v);
        }
        atomicAdd(&sc[bg], 1.0f);
    }
    __syncthreads();
    int bmin = srange[0], bmax = srange[1];
    int rows = bmax - bmin + 1;
    for (int k = threadIdx.x; k < rows * NC; k += blockDim.x) {
        int r = bmin + k / NC, c = k % NC;
        float v = sp[r * NC + c];
        if (v != 0.0f) atomicAdd(&pooled[r * NC + c], v);
    }
    for (int k = threadIdx.x; k < rows; k += blockDim.x) {
        float v = sc[bmin + k];
        if (v != 0.0f) atomicAdd(&cnt[bmin + k], v);
    }
}

// ---------------- mean + log_softmax ----------------
__global__ void logsm_kernel(const float* __restrict__ pooled, const float* __restrict__ cnt,
                             float* __restrict__ out) {
    int gidx = threadIdx.x;
    if (gidx >= NG) return;
    float c = cnt[gidx];
    c = c > 1.0f ? c : 1.0f;
    float v[NC];
    float m = -1e30f;
#pragma unroll
    for (int k = 0; k < NC; ++k) {
        v[k] = pooled[gidx * NC + k] / c;
        m = v[k] > m ? v[k] : m;
    }
    float s = 0.0f;
#pragma unroll
    for (int k = 0; k < NC; ++k) s += expf(v[k] - m);
    float ls = logf(s);
#pragma unroll
    for (int k = 0; k < NC; ++k) out[gidx * NC + k] = v[k] - m - ls;
}

extern "C" void kernel_launch(void* const* d_in, const int* in_sizes, int n_in,
                              void* d_out, int out_size, void* d_ws, size_t ws_size,
                              hipStream_t stream) {
    const float* x     = (const float*)d_in[0];
    const int*   ei    = (const int*)d_in[1];
    const int*   batch = (const int*)d_in[2];
    const float* W[7];
    const float* b[7];
    for (int l = 0; l < 7; ++l) {
        W[l] = (const float*)d_in[3 + 2 * l];
        b[l] = (const float*)d_in[4 + 2 * l];
    }
    const int N = in_sizes[2];
    const int E = in_sizes[1] / 2;
    const int* src = ei;
    const int* dst = ei + E;
    float* out = (float*)d_out;

    float* wsf    = (float*)d_ws;
    float* dinv   = wsf;                       // N
    float* g      = wsf + N;                   // N*HID
    float* acc    = g + (size_t)N * HID;       // N*HID
    float* pooled = acc + (size_t)N * HID;     // NG*NC
    float* cnt    = pooled + NG * NC;          // NG

    hipMemsetAsync(dinv, 0, (size_t)N * sizeof(float), stream);
    hipMemsetAsync(acc, 0, (size_t)N * HID * sizeof(float), stream);
    hipMemsetAsync(pooled, 0, (NG * NC + NG) * sizeof(float), stream);

    const int BT = 256;
    int be = (E + BT - 1) / BT;
    int bn = (N + BT - 1) / BT;

    count_deg_kernel<<<be, BT, 0, stream>>>(dst, dinv, E);
    dinv_kernel<<<bn, BT, 0, stream>>>(dinv, N);

    // layer 1: one wave per node (4 nodes per 256-thread block)
    layer1_kernel<<<(N + 3) / 4, BT, 0, stream>>>(x, W[0], dinv, g, N);

    for (int l = 0; l < 6; ++l) {
        scatter6_kernel<<<be, BT, 0, stream>>>(src, dst, g, acc, E);
        if (l < 5)
            mid_kernel<<<bn, BT, 0, stream>>>(dinv, g, acc, W[l + 1], b[l], N);
        else
            prep7_kernel<<<bn, BT, 0, stream>>>(dinv, g, acc, b[5], N);
    }
    // conv7: scatter in 6 dims, Wf applied in pool kernel
    scatter6_kernel<<<be, BT, 0, stream>>>(src, dst, g, acc, E);
    pool_kernel<<<bn, BT, 0, stream>>>(g, acc, dinv, batch, W[6], b[6], pooled, cnt, N);
    logsm_kernel<<<1, 64, 0, stream>>>(pooled, cnt, out);
}

// Round 2
// 975.290 us; speedup vs baseline: 7.2039x; 7.2039x over previous
//
#include <hip/hip_runtime.h>
#include <hip/hip_bf16.h>
#include <math.h>

#define NF   128
#define HID  6
#define GP   8      // padded row stride for g (32B, two float4)
#define NC   10
#define NG   64

__device__ __forceinline__ void add4(float4& a, const float4 b) {
    a.x += b.x; a.y += b.y; a.z += b.z; a.w += b.w;
}

// ---------------- CSR build: histogram over dst ----------------
__global__ void hist_kernel(const int* __restrict__ dst, int* __restrict__ cnt, int E) {
    int e = blockIdx.x * blockDim.x + threadIdx.x;
    if (e < E) atomicAdd(&cnt[dst[e]], 1);
}

__global__ void dinv_kernel(const int* __restrict__ cnt, float* __restrict__ dinv, int N) {
    int i = blockIdx.x * blockDim.x + threadIdx.x;
    if (i < N) dinv[i] = rsqrtf((float)cnt[i] + 1.0f);  // +1 self loop
}

// single-block chunked exclusive scan (N ~ 100K, 4096/chunk)
__global__ void scan_kernel(const int* __restrict__ cnt, int* __restrict__ row_start,
                            int* __restrict__ cursor, int N) {
    __shared__ int sd[1024];
    __shared__ int carry;
    int tid = threadIdx.x;
    if (tid == 0) carry = 0;
    __syncthreads();
    for (int base = 0; base < N; base += 4096) {
        int idx = base + tid * 4;
        int v0 = (idx + 0 < N) ? cnt[idx + 0] : 0;
        int v1 = (idx + 1 < N) ? cnt[idx + 1] : 0;
        int v2 = (idx + 2 < N) ? cnt[idx + 2] : 0;
        int v3 = (idx + 3 < N) ? cnt[idx + 3] : 0;
        int ts = v0 + v1 + v2 + v3;
        sd[tid] = ts;
        __syncthreads();
        for (int off = 1; off < 1024; off <<= 1) {
            int t = (tid >= off) ? sd[tid - off] : 0;
            __syncthreads();
            sd[tid] += t;
            __syncthreads();
        }
        int incl = sd[tid];
        int ex = incl - ts + carry;
        if (idx + 0 < N) { row_start[idx + 0] = ex;            cursor[idx + 0] = ex; }
        if (idx + 1 < N) { row_start[idx + 1] = ex + v0;       cursor[idx + 1] = ex + v0; }
        if (idx + 2 < N) { row_start[idx + 2] = ex + v0 + v1;  cursor[idx + 2] = ex + v0 + v1; }
        if (idx + 3 < N) { row_start[idx + 3] = ex + v0 + v1 + v2; cursor[idx + 3] = ex + v0 + v1 + v2; }
        __syncthreads();
        if (tid == 1023) carry += incl;
        __syncthreads();
    }
}

__global__ void fill_kernel(const int* __restrict__ src, const int* __restrict__ dst,
                            int* __restrict__ cursor, int* __restrict__ csr, int E) {
    int e = blockIdx.x * blockDim.x + threadIdx.x;
    if (e >= E) return;
    int pos = atomicAdd(&cursor[dst[e]], 1);
    csr[pos] = src[e];
}

// ---------------- layer 1: g = dinv * (x @ W1), one wave per node ----------------
__global__ void layer1_kernel(const float* __restrict__ x, const float* __restrict__ W,
                              const float* __restrict__ dinv, float* __restrict__ g, int N) {
    __shared__ float sW[NF * HID];
    for (int k = threadIdx.x; k < NF * HID; k += blockDim.x) sW[k] = W[k];
    __syncthreads();
    int wave = threadIdx.x >> 6;
    int lane = threadIdx.x & 63;
    int node = blockIdx.x * (blockDim.x >> 6) + wave;
    if (node >= N) return;
    float x0 = x[(size_t)node * NF + lane];
    float x1 = x[(size_t)node * NF + 64 + lane];
    float p[HID];
#pragma unroll
    for (int f = 0; f < HID; ++f)
        p[f] = x0 * sW[lane * HID + f] + x1 * sW[(lane + 64) * HID + f];
#pragma unroll
    for (int off = 32; off > 0; off >>= 1) {
#pragma unroll
        for (int f = 0; f < HID; ++f) p[f] += __shfl_down(p[f], off);
    }
    if (lane == 0) {
        float dv = dinv[node];
#pragma unroll
        for (int f = 0; f < HID; ++f) g[node * GP + f] = dv * p[f];
        g[node * GP + 6] = 0.0f;
        g[node * GP + 7] = 0.0f;
    }
}

// ---------------- fused: gather + epilogue (+ next matmul) ----------------
// PREP=0: gout = dinv * (relu(dinv*(sum+self)+b) @ W)
// PREP=1: gout = dinv *  relu(dinv*(sum+self)+b)
template<int PREP>
__global__ void gcn_layer_kernel(const int* __restrict__ row_start, const int* __restrict__ cnt,
                                 const int* __restrict__ csr, const float* __restrict__ dinv,
                                 const float* __restrict__ gin, float* __restrict__ gout,
                                 const float* __restrict__ W, const float* __restrict__ b, int N) {
    int i = blockIdx.x * blockDim.x + threadIdx.x;
    if (i >= N) return;
    int st = row_start[i];
    int n  = cnt[i];
    const float4* g4 = (const float4*)gin;
    float4 a0 = make_float4(0.f, 0.f, 0.f, 0.f), a1 = a0, c0 = a0, c1 = a0;
    int k = 0;
    for (; k + 1 < n; k += 2) {
        int s0 = csr[st + k];
        int s1 = csr[st + k + 1];
        add4(a0, g4[2 * s0]); add4(a1, g4[2 * s0 + 1]);
        add4(c0, g4[2 * s1]); add4(c1, g4[2 * s1 + 1]);
    }
    if (k < n) {
        int s0 = csr[st + k];
        add4(a0, g4[2 * s0]); add4(a1, g4[2 * s0 + 1]);
    }
    add4(a0, c0); add4(a1, c1);
    float dv = dinv[i];
    float h[HID];
    float self[GP];
    float4 sf0 = g4[2 * i], sf1 = g4[2 * i + 1];
    self[0] = sf0.x; self[1] = sf0.y; self[2] = sf0.z; self[3] = sf0.w;
    self[4] = sf1.x; self[5] = sf1.y;
    float sum[HID] = { a0.x + self[0], a0.y + self[1], a0.z + self[2],
                       a0.w + self[3], a1.x + self[4], a1.y + self[5] };
#pragma unroll
    for (int f = 0; f < HID; ++f) {
        float u = dv * sum[f] + b[f];
        h[f] = u > 0.0f ? u : 0.0f;
    }
    float4 o0, o1;
    if (PREP) {
        o0 = make_float4(dv * h[0], dv * h[1], dv * h[2], dv * h[3]);
        o1 = make_float4(dv * h[4], dv * h[5], 0.f, 0.f);
    } else {
        float o[HID];
#pragma unroll
        for (int fo = 0; fo < HID; ++fo) {
            float s = 0.0f;
#pragma unroll
            for (int fi = 0; fi < HID; ++fi) s += h[fi] * W[fi * HID + fo];
            o[fo] = dv * s;
        }
        o0 = make_float4(o[0], o[1], o[2], o[3]);
        o1 = make_float4(o[4], o[5], 0.f, 0.f);
    }
    ((float4*)gout)[2 * i]     = o0;
    ((float4*)gout)[2 * i + 1] = o1;
}

// ---------------- pool: gather conv7 + Wf + relu + LDS mean-pool ----------------
__global__ void pool_kernel(const int* __restrict__ row_start, const int* __restrict__ cnt,
                            const int* __restrict__ csr, const float* __restrict__ dinv,
                            const float* __restrict__ gin, const int* __restrict__ batch,
                            const float* __restrict__ Wf, const float* __restrict__ bf,
                            float* __restrict__ pooled, float* __restrict__ gcnt, int N) {
    __shared__ float sp[NG * NC];
    __shared__ float sc[NG];
    __shared__ int srange[2];
    for (int k = threadIdx.x; k < NG * NC; k += blockDim.x) sp[k] = 0.0f;
    if (threadIdx.x < NG) sc[threadIdx.x] = 0.0f;
    int start = blockIdx.x * blockDim.x;
    int endi = min(start + (int)blockDim.x, N) - 1;
    if (threadIdx.x == 0) {
        srange[0] = batch[start];   // batch is sorted
        srange[1] = batch[endi];
    }
    __syncthreads();
    int i = start + threadIdx.x;
    if (i < N) {
        int st = row_start[i];
        int n  = cnt[i];
        const float4* g4 = (const float4*)gin;
        float4 a0 = make_float4(0.f, 0.f, 0.f, 0.f), a1 = a0, c0 = a0, c1 = a0;
        int k = 0;
        for (; k + 1 < n; k += 2) {
            int s0 = csr[st + k];
            int s1 = csr[st + k + 1];
            add4(a0, g4[2 * s0]); add4(a1, g4[2 * s0 + 1]);
            add4(c0, g4[2 * s1]); add4(c1, g4[2 * s1 + 1]);
        }
        if (k < n) {
            int s0 = csr[st + k];
            add4(a0, g4[2 * s0]); add4(a1, g4[2 * s0 + 1]);
        }
        add4(a0, c0); add4(a1, c1);
        float dv = dinv[i];
        float4 sf0 = g4[2 * i], sf1 = g4[2 * i + 1];
        float u[HID] = { dv * (a0.x + sf0.x), dv * (a0.y + sf0.y), dv * (a0.z + sf0.z),
                         dv * (a0.w + sf0.w), dv * (a1.x + sf1.x), dv * (a1.y + sf1.y) };
        int bg = batch[i];
#pragma unroll
        for (int c = 0; c < NC; ++c) {
            float v = bf[c];
#pragma unroll
            for (int f = 0; f < HID; ++f) v += u[f] * Wf[f * NC + c];
            v = v > 0.0f ? v : 0.0f;
            atomicAdd(&sp[bg * NC + c], v);
        }
        atomicAdd(&sc[bg], 1.0f);
    }
    __syncthreads();
    int bmin = srange[0], bmax = srange[1];
    int rows = bmax - bmin + 1;
    for (int k = threadIdx.x; k < rows * NC; k += blockDim.x) {
        int r = bmin + k / NC, c = k % NC;
        float v = sp[r * NC + c];
        if (v != 0.0f) atomicAdd(&pooled[r * NC + c], v);
    }
    for (int k = threadIdx.x; k < rows; k += blockDim.x) {
        float v = sc[bmin + k];
        if (v != 0.0f) atomicAdd(&gcnt[bmin + k], v);
    }
}

// ---------------- mean + log_softmax ----------------
__global__ void logsm_kernel(const float* __restrict__ pooled, const float* __restrict__ gcnt,
                             float* __restrict__ out) {
    int gidx = threadIdx.x;
    if (gidx >= NG) return;
    float c = gcnt[gidx];
    c = c > 1.0f ? c : 1.0f;
    float v[NC];
    float m = -1e30f;
#pragma unroll
    for (int k = 0; k < NC; ++k) {
        v[k] = pooled[gidx * NC + k] / c;
        m = v[k] > m ? v[k] : m;
    }
    float s = 0.0f;
#pragma unroll
    for (int k = 0; k < NC; ++k) s += expf(v[k] - m);
    float ls = logf(s);
#pragma unroll
    for (int k = 0; k < NC; ++k) out[gidx * NC + k] = v[k] - m - ls;
}

extern "C" void kernel_launch(void* const* d_in, const int* in_sizes, int n_in,
                              void* d_out, int out_size, void* d_ws, size_t ws_size,
                              hipStream_t stream) {
    const float* x     = (const float*)d_in[0];
    const int*   ei    = (const int*)d_in[1];
    const int*   batch = (const int*)d_in[2];
    const float* W[7];
    const float* b[7];
    for (int l = 0; l < 7; ++l) {
        W[l] = (const float*)d_in[3 + 2 * l];
        b[l] = (const float*)d_in[4 + 2 * l];
    }
    const int N = in_sizes[2];
    const int E = in_sizes[1] / 2;
    const int* src = ei;
    const int* dst = ei + E;
    float* out = (float*)d_out;

    // workspace layout
    char* wp = (char*)d_ws;
    int* cnt       = (int*)wp;              wp += (size_t)N * sizeof(int);
    int* row_start = (int*)wp;              wp += (size_t)N * sizeof(int);
    int* cursor    = (int*)wp;              wp += (size_t)N * sizeof(int);
    int* csr       = (int*)wp;              wp += (size_t)E * sizeof(int);
    float* dinv    = (float*)wp;            wp += (size_t)N * sizeof(float);
    float* g_a     = (float*)wp;            wp += (size_t)N * GP * sizeof(float);
    float* g_b     = (float*)wp;            wp += (size_t)N * GP * sizeof(float);
    float* pooled  = (float*)wp;            wp += NG * NC * sizeof(float);
    float* gcnt    = (float*)wp;            wp += NG * sizeof(float);

    hipMemsetAsync(cnt, 0, (size_t)N * sizeof(int), stream);
    hipMemsetAsync(pooled, 0, (NG * NC + NG) * sizeof(float), stream);

    const int BT = 256;
    int be = (E + BT - 1) / BT;
    int bn = (N + BT - 1) / BT;

    hist_kernel<<<be, BT, 0, stream>>>(dst, cnt, E);
    dinv_kernel<<<bn, BT, 0, stream>>>(cnt, dinv, N);
    scan_kernel<<<1, 1024, 0, stream>>>(cnt, row_start, cursor, N);
    fill_kernel<<<be, BT, 0, stream>>>(src, dst, cursor, csr, E);

    layer1_kernel<<<(N + 3) / 4, BT, 0, stream>>>(x, W[0], dinv, g_a, N);

    // 5 mid layers: (b1,W2) .. (b5,W6), alternating g buffers
    gcn_layer_kernel<0><<<bn, BT, 0, stream>>>(row_start, cnt, csr, dinv, g_a, g_b, W[1], b[0], N);
    gcn_layer_kernel<0><<<bn, BT, 0, stream>>>(row_start, cnt, csr, dinv, g_b, g_a, W[2], b[1], N);
    gcn_layer_kernel<0><<<bn, BT, 0, stream>>>(row_start, cnt, csr, dinv, g_a, g_b, W[3], b[2], N);
    gcn_layer_kernel<0><<<bn, BT, 0, stream>>>(row_start, cnt, csr, dinv, g_b, g_a, W[4], b[3], N);
    gcn_layer_kernel<0><<<bn, BT, 0, stream>>>(row_start, cnt, csr, dinv, g_a, g_b, W[5], b[4], N);
    // layer 6 epilogue (b6), no next W
    gcn_layer_kernel<1><<<bn, BT, 0, stream>>>(row_start, cnt, csr, dinv, g_b, g_a, nullptr, b[5], N);
    // conv7 gather + Wf + bf + relu + pool
    pool_kernel<<<bn, BT, 0, stream>>>(row_start, cnt, csr, dinv, g_a, batch, W[6], b[6], pooled, gcnt, N);
    logsm_kernel<<<1, 64, 0, stream>>>(pooled, gcnt, out);
}

// Round 3
// 736.028 us; speedup vs baseline: 9.5457x; 1.3251x over previous
//
#include <hip/hip_runtime.h>
#include <hip/hip_bf16.h>
#include <math.h>

#define NF     128
#define HID    6
#define GP     8      // padded row stride for g (32B, two float4)
#define NC     10
#define NG     64
#define SLOTS  64     // ELL row capacity (deg ~ Poisson(32); P(deg>64) ~ 4e-7/node)
#define OVFCAP 8192

__device__ __forceinline__ void add4(float4& a, const float4 b) {
    a.x += b.x; a.y += b.y; a.z += b.z; a.w += b.w;
}

// ---------------- ELL build: one atomic pass, no hist/scan ----------------
__global__ void ell_fill_kernel(const int* __restrict__ src, const int* __restrict__ dst,
                                int* __restrict__ cursor, int* __restrict__ ell,
                                int* __restrict__ ovf_meta, int* __restrict__ ovf_dst,
                                int* __restrict__ ovf_src, int E) {
    int e = blockIdx.x * blockDim.x + threadIdx.x;
    if (e >= E) return;
    int s = src[e];
    int d = dst[e];
    int slot = atomicAdd(&cursor[d], 1);
    if (slot < SLOTS) {
        ell[(size_t)d * SLOTS + slot] = s;
    } else {
        int pos = atomicAdd(&ovf_meta[0], 1);
        if (pos < OVFCAP) { ovf_dst[pos] = d; ovf_src[pos] = s; }
    }
}

__global__ void dinv_kernel(const int* __restrict__ cnt, float* __restrict__ dinv, int N) {
    int i = blockIdx.x * blockDim.x + threadIdx.x;
    if (i < N) dinv[i] = rsqrtf((float)cnt[i] + 1.0f);  // +1 self loop
}

// ---------------- layer 1: g = dinv * (x @ W1), one wave per node ----------------
__global__ void layer1_kernel(const float* __restrict__ x, const float* __restrict__ W,
                              const float* __restrict__ dinv, float* __restrict__ g, int N) {
    __shared__ float sW[NF * HID];
    for (int k = threadIdx.x; k < NF * HID; k += blockDim.x) sW[k] = W[k];
    __syncthreads();
    int wave = threadIdx.x >> 6;
    int lane = threadIdx.x & 63;
    int node = blockIdx.x * (blockDim.x >> 6) + wave;
    if (node >= N) return;
    float x0 = x[(size_t)node * NF + lane];
    float x1 = x[(size_t)node * NF + 64 + lane];
    float p[HID];
#pragma unroll
    for (int f = 0; f < HID; ++f)
        p[f] = x0 * sW[lane * HID + f] + x1 * sW[(lane + 64) * HID + f];
#pragma unroll
    for (int off = 32; off > 0; off >>= 1) {
#pragma unroll
        for (int f = 0; f < HID; ++f) p[f] += __shfl_down(p[f], off);
    }
    if (lane == 0) {
        float dv = dinv[node];
#pragma unroll
        for (int f = 0; f < HID; ++f) g[node * GP + f] = dv * p[f];
        g[node * GP + 6] = 0.0f;
        g[node * GP + 7] = 0.0f;
    }
}

// ---------------- neighbor accumulate over one ELL row (+rare overflow) ----------------
__device__ __forceinline__ void gather_row(int i, int n, const int* __restrict__ ell,
                                           const float4* __restrict__ g4,
                                           const int* __restrict__ ovf_meta,
                                           const int* __restrict__ ovf_dst,
                                           const int* __restrict__ ovf_src,
                                           float4& a0, float4& a1) {
    const int4* er = (const int4*)(ell + (size_t)i * SLOTS);
    int ne = n < SLOTS ? n : SLOTS;
    float4 c0 = make_float4(0.f, 0.f, 0.f, 0.f), c1 = c0;
    int full = ne >> 2;
    for (int c = 0; c < full; ++c) {
        int4 q = er[c];
        add4(a0, g4[2 * q.x]); add4(a1, g4[2 * q.x + 1]);
        add4(c0, g4[2 * q.y]); add4(c1, g4[2 * q.y + 1]);
        add4(a0, g4[2 * q.z]); add4(a1, g4[2 * q.z + 1]);
        add4(c0, g4[2 * q.w]); add4(c1, g4[2 * q.w + 1]);
    }
    int rem = ne & 3;
    if (rem) {
        int4 q = er[full];
        add4(a0, g4[2 * q.x]); add4(a1, g4[2 * q.x + 1]);
        if (rem > 1) { add4(c0, g4[2 * q.y]); add4(c1, g4[2 * q.y + 1]); }
        if (rem > 2) { add4(a0, g4[2 * q.z]); add4(a1, g4[2 * q.z + 1]); }
    }
    if (n > SLOTS) {  // ~never taken; correct fallback for deg>SLOTS
        int m = ovf_meta[0];
        m = m < OVFCAP ? m : OVFCAP;
        for (int t = 0; t < m; ++t) {
            if (ovf_dst[t] == i) {
                int s = ovf_src[t];
                add4(a0, g4[2 * s]); add4(a1, g4[2 * s + 1]);
            }
        }
    }
    add4(a0, c0); add4(a1, c1);
}

// ---------------- fused: gather + epilogue (+ next matmul) ----------------
// PREP=0: gout = dinv * (relu(dinv*(sum+self)+b) @ W)
// PREP=1: gout = dinv *  relu(dinv*(sum+self)+b)
template<int PREP>
__global__ void gcn_layer_kernel(const int* __restrict__ cnt, const int* __restrict__ ell,
                                 const int* __restrict__ ovf_meta, const int* __restrict__ ovf_dst,
                                 const int* __restrict__ ovf_src, const float* __restrict__ dinv,
                                 const float* __restrict__ gin, float* __restrict__ gout,
                                 const float* __restrict__ W, const float* __restrict__ b, int N) {
    int i = blockIdx.x * blockDim.x + threadIdx.x;
    if (i >= N) return;
    int n = cnt[i];
    const float4* g4 = (const float4*)gin;
    float4 a0 = make_float4(0.f, 0.f, 0.f, 0.f), a1 = a0;
    gather_row(i, n, ell, g4, ovf_meta, ovf_dst, ovf_src, a0, a1);
    float dv = dinv[i];
    float4 sf0 = g4[2 * i], sf1 = g4[2 * i + 1];
    float sum[HID] = { a0.x + sf0.x, a0.y + sf0.y, a0.z + sf0.z,
                       a0.w + sf0.w, a1.x + sf1.x, a1.y + sf1.y };
    float h[HID];
#pragma unroll
    for (int f = 0; f < HID; ++f) {
        float u = dv * sum[f] + b[f];
        h[f] = u > 0.0f ? u : 0.0f;
    }
    float4 o0, o1;
    if (PREP) {
        o0 = make_float4(dv * h[0], dv * h[1], dv * h[2], dv * h[3]);
        o1 = make_float4(dv * h[4], dv * h[5], 0.f, 0.f);
    } else {
        float o[HID];
#pragma unroll
        for (int fo = 0; fo < HID; ++fo) {
            float s = 0.0f;
#pragma unroll
            for (int fi = 0; fi < HID; ++fi) s += h[fi] * W[fi * HID + fo];
            o[fo] = dv * s;
        }
        o0 = make_float4(o[0], o[1], o[2], o[3]);
        o1 = make_float4(o[4], o[5], 0.f, 0.f);
    }
    ((float4*)gout)[2 * i]     = o0;
    ((float4*)gout)[2 * i + 1] = o1;
}

// ---------------- pool: gather conv7 + Wf + relu + LDS mean-pool ----------------
__global__ void pool_kernel(const int* __restrict__ cnt, const int* __restrict__ ell,
                            const int* __restrict__ ovf_meta, const int* __restrict__ ovf_dst,
                            const int* __restrict__ ovf_src, const float* __restrict__ dinv,
                            const float* __restrict__ gin, const int* __restrict__ batch,
                            const float* __restrict__ Wf, const float* __restrict__ bf,
                            float* __restrict__ pooled, float* __restrict__ gcnt, int N) {
    __shared__ float sp[NG * NC];
    __shared__ float sc[NG];
    __shared__ int srange[2];
    for (int k = threadIdx.x; k < NG * NC; k += blockDim.x) sp[k] = 0.0f;
    if (threadIdx.x < NG) sc[threadIdx.x] = 0.0f;
    int start = blockIdx.x * blockDim.x;
    int endi = min(start + (int)blockDim.x, N) - 1;
    if (threadIdx.x == 0) {
        srange[0] = batch[start];   // batch is sorted
        srange[1] = batch[endi];
    }
    __syncthreads();
    int i = start + threadIdx.x;
    if (i < N) {
        int n = cnt[i];
        const float4* g4 = (const float4*)gin;
        float4 a0 = make_float4(0.f, 0.f, 0.f, 0.f), a1 = a0;
        gather_row(i, n, ell, g4, ovf_meta, ovf_dst, ovf_src, a0, a1);
        float dv = dinv[i];
        float4 sf0 = g4[2 * i], sf1 = g4[2 * i + 1];
        float u[HID] = { dv * (a0.x + sf0.x), dv * (a0.y + sf0.y), dv * (a0.z + sf0.z),
                         dv * (a0.w + sf0.w), dv * (a1.x + sf1.x), dv * (a1.y + sf1.y) };
        int bg = batch[i];
#pragma unroll
        for (int c = 0; c < NC; ++c) {
            float v = bf[c];
#pragma unroll
            for (int f = 0; f < HID; ++f) v += u[f] * Wf[f * NC + c];
            v = v > 0.0f ? v : 0.0f;
            atomicAdd(&sp[bg * NC + c], v);
        }
        atomicAdd(&sc[bg], 1.0f);
    }
    __syncthreads();
    int bmin = srange[0], bmax = srange[1];
    int rows = bmax - bmin + 1;
    for (int k = threadIdx.x; k < rows * NC; k += blockDim.x) {
        int r = bmin + k / NC, c = k % NC;
        float v = sp[r * NC + c];
        if (v != 0.0f) atomicAdd(&pooled[r * NC + c], v);
    }
    for (int k = threadIdx.x; k < rows; k += blockDim.x) {
        float v = sc[bmin + k];
        if (v != 0.0f) atomicAdd(&gcnt[bmin + k], v);
    }
}

// ---------------- mean + log_softmax ----------------
__global__ void logsm_kernel(const float* __restrict__ pooled, const float* __restrict__ gcnt,
                             float* __restrict__ out) {
    int gidx = threadIdx.x;
    if (gidx >= NG) return;
    float c = gcnt[gidx];
    c = c > 1.0f ? c : 1.0f;
    float v[NC];
    float m = -1e30f;
#pragma unroll
    for (int k = 0; k < NC; ++k) {
        v[k] = pooled[gidx * NC + k] / c;
        m = v[k] > m ? v[k] : m;
    }
    float s = 0.0f;
#pragma unroll
    for (int k = 0; k < NC; ++k) s += expf(v[k] - m);
    float ls = logf(s);
#pragma unroll
    for (int k = 0; k < NC; ++k) out[gidx * NC + k] = v[k] - m - ls;
}

extern "C" void kernel_launch(void* const* d_in, const int* in_sizes, int n_in,
                              void* d_out, int out_size, void* d_ws, size_t ws_size,
                              hipStream_t stream) {
    const float* x     = (const float*)d_in[0];
    const int*   ei    = (const int*)d_in[1];
    const int*   batch = (const int*)d_in[2];
    const float* W[7];
    const float* b[7];
    for (int l = 0; l < 7; ++l) {
        W[l] = (const float*)d_in[3 + 2 * l];
        b[l] = (const float*)d_in[4 + 2 * l];
    }
    const int N = in_sizes[2];
    const int E = in_sizes[1] / 2;
    const int* src = ei;
    const int* dst = ei + E;
    float* out = (float*)d_out;

    // workspace layout (16B-aligned blocks)
    char* wp = (char*)d_ws;
    int* cursor   = (int*)wp;   wp += ((size_t)N * 4 + 15 & ~15ull);
    int* ovf_meta = (int*)wp;   wp += 16;
    int* ovf_dst  = (int*)wp;   wp += OVFCAP * 4;
    int* ovf_src  = (int*)wp;   wp += OVFCAP * 4;
    float* dinv   = (float*)wp; wp += ((size_t)N * 4 + 15 & ~15ull);
    float* g_a    = (float*)wp; wp += (size_t)N * GP * 4;
    float* g_b    = (float*)wp; wp += (size_t)N * GP * 4;
    float* pooled = (float*)wp; wp += NG * NC * 4;
    float* gcnt   = (float*)wp; wp += ((size_t)NG * 4 + 15 & ~15ull);
    int* ell      = (int*)wp;   wp += (size_t)N * SLOTS * 4;

    hipMemsetAsync(cursor, 0, (size_t)N * sizeof(int) + 16, stream);  // cursor + ovf_meta
    hipMemsetAsync(pooled, 0, (NG * NC + NG) * sizeof(float), stream);

    const int BT = 256;
    int be = (E + BT - 1) / BT;
    int bn = (N + BT - 1) / BT;

    ell_fill_kernel<<<be, BT, 0, stream>>>(src, dst, cursor, ell, ovf_meta, ovf_dst, ovf_src, E);
    dinv_kernel<<<bn, BT, 0, stream>>>(cursor, dinv, N);

    layer1_kernel<<<(N + 3) / 4, BT, 0, stream>>>(x, W[0], dinv, g_a, N);

    // 5 mid layers: (b1,W2) .. (b5,W6), alternating g buffers
    gcn_layer_kernel<0><<<bn, BT, 0, stream>>>(cursor, ell, ovf_meta, ovf_dst, ovf_src, dinv, g_a, g_b, W[1], b[0], N);
    gcn_layer_kernel<0><<<bn, BT, 0, stream>>>(cursor, ell, ovf_meta, ovf_dst, ovf_src, dinv, g_b, g_a, W[2], b[1], N);
    gcn_layer_kernel<0><<<bn, BT, 0, stream>>>(cursor, ell, ovf_meta, ovf_dst, ovf_src, dinv, g_a, g_b, W[3], b[2], N);
    gcn_layer_kernel<0><<<bn, BT, 0, stream>>>(cursor, ell, ovf_meta, ovf_dst, ovf_src, dinv, g_b, g_a, W[4], b[3], N);
    gcn_layer_kernel<0><<<bn, BT, 0, stream>>>(cursor, ell, ovf_meta, ovf_dst, ovf_src, dinv, g_a, g_b, W[5], b[4], N);
    // layer 6 epilogue (b6), no next W
    gcn_layer_kernel<1><<<bn, BT, 0, stream>>>(cursor, ell, ovf_meta, ovf_dst, ovf_src, dinv, g_b, g_a, nullptr, b[5], N);
    // conv7 gather + Wf + bf + relu + pool
    pool_kernel<<<bn, BT, 0, stream>>>(cursor, ell, ovf_meta, ovf_dst, ovf_src, dinv, g_a, batch, W[6], b[6], pooled, gcnt, N);
    logsm_kernel<<<1, 64, 0, stream>>>(pooled, gcnt, out);
}

// Round 4
// 496.373 us; speedup vs baseline: 14.1545x; 1.4828x over previous
//
#include <hip/hip_runtime.h>
#include <hip/hip_bf16.h>
#include <math.h>

#define NF     128
#define HID    6
#define GP     8      // padded row stride for g (32B, two float4)
#define NC     10
#define NG     64
#define SLOTS  64     // ELL row capacity (deg ~ Poisson(32); P(deg>64) ~ 4e-7/node)
#define OVFCAP 8192

// bucket build params
#define BKT_SH    7
#define BKT_NODES 128
#define NBK_MAX   1024     // supports N <= 131072
#define EPB       4096     // edges per phase-1 block (256 thr x 16)
#define BCAP      5120     // per-bucket capacity (mean 4096, +16 sigma)
#define BOVFCAP   4096

__device__ __forceinline__ void add4(float4& a, const float4 b) {
    a.x += b.x; a.y += b.y; a.z += b.z; a.w += b.w;
}

// ---------------- phase 1: bin edges by dst>>7 with LDS ranking, semi-coalesced out ----------------
__global__ __launch_bounds__(256) void bucket_scatter_kernel(
        const int* __restrict__ src, const int* __restrict__ dst, int E, int nbk,
        int* __restrict__ bucket_cursor, unsigned int* __restrict__ bucket_arr,
        int* __restrict__ bovf_meta, int2* __restrict__ bovf) {
    __shared__ int cntL[NBK_MAX];
    __shared__ int offs[NBK_MAX];
    __shared__ int curL[NBK_MAX];
    __shared__ int gb[NBK_MAX];
    __shared__ int scanbuf[256];
    __shared__ unsigned int stage[EPB];
    __shared__ int gaddr[EPB];
    int tid = threadIdx.x;
    for (int k = tid; k < NBK_MAX; k += 256) cntL[k] = 0;
    __syncthreads();
    int e0 = blockIdx.x * EPB;
    int cnt_e = E - e0; if (cnt_e > EPB) cnt_e = EPB;
    int sreg[16], dreg[16];
    // pass A: count
#pragma unroll
    for (int k = 0; k < 16; ++k) {
        int e = e0 + k * 256 + tid;
        if (e < E) {
            int d = dst[e], s = src[e];
            sreg[k] = s; dreg[k] = d;
            atomicAdd(&cntL[d >> BKT_SH], 1);
        } else dreg[k] = -1;
    }
    __syncthreads();
    // exclusive block scan over NBK_MAX entries (4 per thread + Hillis-Steele on totals)
    int base = tid * 4;
    int c0 = cntL[base], c1 = cntL[base + 1], c2 = cntL[base + 2], c3 = cntL[base + 3];
    int tsum = c0 + c1 + c2 + c3;
    scanbuf[tid] = tsum;
    __syncthreads();
    for (int off = 1; off < 256; off <<= 1) {
        int v = (tid >= off) ? scanbuf[tid - off] : 0;
        __syncthreads();
        scanbuf[tid] += v;
        __syncthreads();
    }
    int ex = scanbuf[tid] - tsum;
    offs[base] = ex;
    offs[base + 1] = ex + c0;
    offs[base + 2] = ex + c0 + c1;
    offs[base + 3] = ex + c0 + c1 + c2;
    curL[base] = offs[base];
    curL[base + 1] = offs[base + 1];
    curL[base + 2] = offs[base + 2];
    curL[base + 3] = offs[base + 3];
    __syncthreads();
    // reserve global spans (one atomic per non-empty bucket per block)
    for (int b = tid; b < nbk; b += 256) {
        int c = cntL[b];
        if (c > 0) gb[b] = atomicAdd(&bucket_cursor[b], c);
    }
    __syncthreads();
    // pass B: rank into LDS staging
#pragma unroll
    for (int k = 0; k < 16; ++k) {
        int d = dreg[k];
        if (d < 0) continue;
        int s = sreg[k];
        int b = d >> BKT_SH;
        int pos = atomicAdd(&curL[b], 1);
        int rel = gb[b] + (pos - offs[b]);
        stage[pos] = (unsigned int)(d & (BKT_NODES - 1)) | ((unsigned int)s << BKT_SH);
        if (rel < BCAP) {
            gaddr[pos] = b * BCAP + rel;
        } else {  // bucket capacity overflow (~never)
            gaddr[pos] = -1;
            int p2 = atomicAdd(bovf_meta, 1);
            if (p2 < BOVFCAP) bovf[p2] = make_int2(d, s);
        }
    }
    __syncthreads();
    // copy out: consecutive j -> consecutive addresses within runs (semi-coalesced)
    for (int j = tid; j < cnt_e; j += 256) {
        int ga = gaddr[j];
        if (ga >= 0) bucket_arr[ga] = stage[j];
    }
}

// ---------------- phase 2: per-bucket ELL build in LDS, coalesced dump ----------------
__global__ __launch_bounds__(256) void ell_build_kernel(
        const unsigned int* __restrict__ bucket_arr, const int* __restrict__ bucket_cursor,
        const int* __restrict__ bovf_meta, const int2* __restrict__ bovf,
        int* __restrict__ ell, int* __restrict__ cnt,
        int* __restrict__ ovf_meta, int* __restrict__ ovf_dst, int* __restrict__ ovf_src,
        int N) {
    __shared__ int ell_s[BKT_NODES * SLOTS];   // 32KB
    __shared__ int cur[BKT_NODES];
    int b = blockIdx.x;
    int tid = threadIdx.x;
    if (tid < BKT_NODES) cur[tid] = 0;
    __syncthreads();
    int bc = bucket_cursor[b];
    if (bc > BCAP) bc = BCAP;
    const unsigned int* ba = bucket_arr + (size_t)b * BCAP;
    for (int j = tid; j < bc; j += 256) {
        unsigned int p = ba[j];
        int r = (int)(p & (BKT_NODES - 1));
        int s = (int)(p >> BKT_SH);
        int slot = atomicAdd(&cur[r], 1);
        if (slot < SLOTS) {
            ell_s[r * SLOTS + slot] = s;
        } else {  // node degree overflow (~never)
            int d = (b << BKT_SH) + r;
            int q = atomicAdd(ovf_meta, 1);
            if (q < OVFCAP) { ovf_dst[q] = d; ovf_src[q] = s; }
        }
    }
    // fold in bucket-capacity overflow edges (list is ~always empty)
    int m = *bovf_meta;
    if (m > BOVFCAP) m = BOVFCAP;
    for (int t = tid; t < m; t += 256) {
        int2 e = bovf[t];
        if ((e.x >> BKT_SH) == b) {
            int r = e.x & (BKT_NODES - 1);
            int slot = atomicAdd(&cur[r], 1);
            if (slot < SLOTS) {
                ell_s[r * SLOTS + slot] = e.y;
            } else {
                int q = atomicAdd(ovf_meta, 1);
                if (q < OVFCAP) { ovf_dst[q] = e.x; ovf_src[q] = e.y; }
            }
        }
    }
    __syncthreads();
    int nid0 = b << BKT_SH;
    int rows = N - nid0; if (rows > BKT_NODES) rows = BKT_NODES;
    if (rows <= 0) return;
    int4* eg = (int4*)(ell + (size_t)nid0 * SLOTS);
    const int4* es = (const int4*)ell_s;
    for (int k = tid; k < rows * (SLOTS / 4); k += 256) eg[k] = es[k];
    for (int r = tid; r < rows; r += 256) cnt[nid0 + r] = cur[r];
}

__global__ void dinv_kernel(const int* __restrict__ cnt, float* __restrict__ dinv, int N) {
    int i = blockIdx.x * blockDim.x + threadIdx.x;
    if (i < N) dinv[i] = rsqrtf((float)cnt[i] + 1.0f);  // +1 self loop
}

// ---------------- layer 1: g = dinv * (x @ W1), one wave per node ----------------
__global__ void layer1_kernel(const float* __restrict__ x, const float* __restrict__ W,
                              const float* __restrict__ dinv, float* __restrict__ g, int N) {
    __shared__ float sW[NF * HID];
    for (int k = threadIdx.x; k < NF * HID; k += blockDim.x) sW[k] = W[k];
    __syncthreads();
    int wave = threadIdx.x >> 6;
    int lane = threadIdx.x & 63;
    int node = blockIdx.x * (blockDim.x >> 6) + wave;
    if (node >= N) return;
    float x0 = x[(size_t)node * NF + lane];
    float x1 = x[(size_t)node * NF + 64 + lane];
    float p[HID];
#pragma unroll
    for (int f = 0; f < HID; ++f)
        p[f] = x0 * sW[lane * HID + f] + x1 * sW[(lane + 64) * HID + f];
#pragma unroll
    for (int off = 32; off > 0; off >>= 1) {
#pragma unroll
        for (int f = 0; f < HID; ++f) p[f] += __shfl_down(p[f], off);
    }
    if (lane == 0) {
        float dv = dinv[node];
#pragma unroll
        for (int f = 0; f < HID; ++f) g[node * GP + f] = dv * p[f];
        g[node * GP + 6] = 0.0f;
        g[node * GP + 7] = 0.0f;
    }
}

// ---------------- neighbor accumulate over one ELL row (+rare overflow) ----------------
__device__ __forceinline__ void gather_row(int i, int n, const int* __restrict__ ell,
                                           const float4* __restrict__ g4,
                                           const int* __restrict__ ovf_meta,
                                           const int* __restrict__ ovf_dst,
                                           const int* __restrict__ ovf_src,
                                           float4& a0, float4& a1) {
    const int4* er = (const int4*)(ell + (size_t)i * SLOTS);
    int ne = n < SLOTS ? n : SLOTS;
    float4 c0 = make_float4(0.f, 0.f, 0.f, 0.f), c1 = c0;
    int full = ne >> 2;
    for (int c = 0; c < full; ++c) {
        int4 q = er[c];
        add4(a0, g4[2 * q.x]); add4(a1, g4[2 * q.x + 1]);
        add4(c0, g4[2 * q.y]); add4(c1, g4[2 * q.y + 1]);
        add4(a0, g4[2 * q.z]); add4(a1, g4[2 * q.z + 1]);
        add4(c0, g4[2 * q.w]); add4(c1, g4[2 * q.w + 1]);
    }
    int rem = ne & 3;
    if (rem) {
        int4 q = er[full];
        add4(a0, g4[2 * q.x]); add4(a1, g4[2 * q.x + 1]);
        if (rem > 1) { add4(c0, g4[2 * q.y]); add4(c1, g4[2 * q.y + 1]); }
        if (rem > 2) { add4(a0, g4[2 * q.z]); add4(a1, g4[2 * q.z + 1]); }
    }
    if (n > SLOTS) {  // ~never taken; correct fallback for deg>SLOTS
        int m = ovf_meta[0];
        m = m < OVFCAP ? m : OVFCAP;
        for (int t = 0; t < m; ++t) {
            if (ovf_dst[t] == i) {
                int s = ovf_src[t];
                add4(a0, g4[2 * s]); add4(a1, g4[2 * s + 1]);
            }
        }
    }
    add4(a0, c0); add4(a1, c1);
}

// ---------------- fused: gather + epilogue (+ next matmul) ----------------
// PREP=0: gout = dinv * (relu(dinv*(sum+self)+b) @ W)
// PREP=1: gout = dinv *  relu(dinv*(sum+self)+b)
template<int PREP>
__global__ void gcn_layer_kernel(const int* __restrict__ cnt, const int* __restrict__ ell,
                                 const int* __restrict__ ovf_meta, const int* __restrict__ ovf_dst,
                                 const int* __restrict__ ovf_src, const float* __restrict__ dinv,
                                 const float* __restrict__ gin, float* __restrict__ gout,
                                 const float* __restrict__ W, const float* __restrict__ b, int N) {
    int i = blockIdx.x * blockDim.x + threadIdx.x;
    if (i >= N) return;
    int n = cnt[i];
    const float4* g4 = (const float4*)gin;
    float4 a0 = make_float4(0.f, 0.f, 0.f, 0.f), a1 = a0;
    gather_row(i, n, ell, g4, ovf_meta, ovf_dst, ovf_src, a0, a1);
    float dv = dinv[i];
    float4 sf0 = g4[2 * i], sf1 = g4[2 * i + 1];
    float sum[HID] = { a0.x + sf0.x, a0.y + sf0.y, a0.z + sf0.z,
                       a0.w + sf0.w, a1.x + sf1.x, a1.y + sf1.y };
    float h[HID];
#pragma unroll
    for (int f = 0; f < HID; ++f) {
        float u = dv * sum[f] + b[f];
        h[f] = u > 0.0f ? u : 0.0f;
    }
    float4 o0, o1;
    if (PREP) {
        o0 = make_float4(dv * h[0], dv * h[1], dv * h[2], dv * h[3]);
        o1 = make_float4(dv * h[4], dv * h[5], 0.f, 0.f);
    } else {
        float o[HID];
#pragma unroll
        for (int fo = 0; fo < HID; ++fo) {
            float s = 0.0f;
#pragma unroll
            for (int fi = 0; fi < HID; ++fi) s += h[fi] * W[fi * HID + fo];
            o[fo] = dv * s;
        }
        o0 = make_float4(o[0], o[1], o[2], o[3]);
        o1 = make_float4(o[4], o[5], 0.f, 0.f);
    }
    ((float4*)gout)[2 * i]     = o0;
    ((float4*)gout)[2 * i + 1] = o1;
}

// ---------------- pool: gather conv7 + Wf + relu + LDS mean-pool ----------------
__global__ void pool_kernel(const int* __restrict__ cnt, const int* __restrict__ ell,
                            const int* __restrict__ ovf_meta, const int* __restrict__ ovf_dst,
                            const int* __restrict__ ovf_src, const float* __restrict__ dinv,
                            const float* __restrict__ gin, const int* __restrict__ batch,
                            const float* __restrict__ Wf, const float* __restrict__ bf,
                            float* __restrict__ pooled, float* __restrict__ gcnt, int N) {
    __shared__ float sp[NG * NC];
    __shared__ float sc[NG];
    __shared__ int srange[2];
    for (int k = threadIdx.x; k < NG * NC; k += blockDim.x) sp[k] = 0.0f;
    if (threadIdx.x < NG) sc[threadIdx.x] = 0.0f;
    int start = blockIdx.x * blockDim.x;
    int endi = min(start + (int)blockDim.x, N) - 1;
    if (threadIdx.x == 0) {
        srange[0] = batch[start];   // batch is sorted
        srange[1] = batch[endi];
    }
    __syncthreads();
    int i = start + threadIdx.x;
    if (i < N) {
        int n = cnt[i];
        const float4* g4 = (const float4*)gin;
        float4 a0 = make_float4(0.f, 0.f, 0.f, 0.f), a1 = a0;
        gather_row(i, n, ell, g4, ovf_meta, ovf_dst, ovf_src, a0, a1);
        float dv = dinv[i];
        float4 sf0 = g4[2 * i], sf1 = g4[2 * i + 1];
        float u[HID] = { dv * (a0.x + sf0.x), dv * (a0.y + sf0.y), dv * (a0.z + sf0.z),
                         dv * (a0.w + sf0.w), dv * (a1.x + sf1.x), dv * (a1.y + sf1.y) };
        int bg = batch[i];
#pragma unroll
        for (int c = 0; c < NC; ++c) {
            float v = bf[c];
#pragma unroll
            for (int f = 0; f < HID; ++f) v += u[f] * Wf[f * NC + c];
            v = v > 0.0f ? v : 0.0f;
            atomicAdd(&sp[bg * NC + c], v);
        }
        atomicAdd(&sc[bg], 1.0f);
    }
    __syncthreads();
    int bmin = srange[0], bmax = srange[1];
    int rows = bmax - bmin + 1;
    for (int k = threadIdx.x; k < rows * NC; k += blockDim.x) {
        int r = bmin + k / NC, c = k % NC;
        float v = sp[r * NC + c];
        if (v != 0.0f) atomicAdd(&pooled[r * NC + c], v);
    }
    for (int k = threadIdx.x; k < rows; k += blockDim.x) {
        float v = sc[bmin + k];
        if (v != 0.0f) atomicAdd(&gcnt[bmin + k], v);
    }
}

// ---------------- mean + log_softmax ----------------
__global__ void logsm_kernel(const float* __restrict__ pooled, const float* __restrict__ gcnt,
                             float* __restrict__ out) {
    int gidx = threadIdx.x;
    if (gidx >= NG) return;
    float c = gcnt[gidx];
    c = c > 1.0f ? c : 1.0f;
    float v[NC];
    float m = -1e30f;
#pragma unroll
    for (int k = 0; k < NC; ++k) {
        v[k] = pooled[gidx * NC + k] / c;
        m = v[k] > m ? v[k] : m;
    }
    float s = 0.0f;
#pragma unroll
    for (int k = 0; k < NC; ++k) s += expf(v[k] - m);
    float ls = logf(s);
#pragma unroll
    for (int k = 0; k < NC; ++k) out[gidx * NC + k] = v[k] - m - ls;
}

extern "C" void kernel_launch(void* const* d_in, const int* in_sizes, int n_in,
                              void* d_out, int out_size, void* d_ws, size_t ws_size,
                              hipStream_t stream) {
    const float* x     = (const float*)d_in[0];
    const int*   ei    = (const int*)d_in[1];
    const int*   batch = (const int*)d_in[2];
    const float* W[7];
    const float* b[7];
    for (int l = 0; l < 7; ++l) {
        W[l] = (const float*)d_in[3 + 2 * l];
        b[l] = (const float*)d_in[4 + 2 * l];
    }
    const int N = in_sizes[2];
    const int E = in_sizes[1] / 2;
    const int nbk = (N + BKT_NODES - 1) >> BKT_SH;
    const int* src = ei;
    const int* dst = ei + E;
    float* out = (float*)d_out;

    // workspace layout (16B-aligned blocks)
    char* wp = (char*)d_ws;
    int* bucket_cursor = (int*)wp;  wp += (size_t)NBK_MAX * 4;
    int* ovf_meta  = (int*)wp;      wp += 16;
    int* bovf_meta = (int*)wp;      wp += 16;   // metas contiguous with cursor -> one memset
    int* ovf_dst   = (int*)wp;      wp += OVFCAP * 4;
    int* ovf_src   = (int*)wp;      wp += OVFCAP * 4;
    int2* bovf     = (int2*)wp;     wp += (size_t)BOVFCAP * 8;
    int* cnt       = (int*)wp;      wp += (((size_t)N * 4 + 15) & ~15ull);
    float* dinv    = (float*)wp;    wp += (((size_t)N * 4 + 15) & ~15ull);
    float* g_a     = (float*)wp;    wp += (size_t)N * GP * 4;
    float* g_b     = (float*)wp;    wp += (size_t)N * GP * 4;
    float* pooled  = (float*)wp;    wp += NG * NC * 4;
    float* gcnt    = (float*)wp;    wp += (((size_t)NG * 4 + 15) & ~15ull);
    int* ell       = (int*)wp;      wp += (size_t)N * SLOTS * 4;
    unsigned int* bucket_arr = (unsigned int*)wp;  wp += (size_t)nbk * BCAP * 4;

    hipMemsetAsync(bucket_cursor, 0, (size_t)NBK_MAX * 4 + 32, stream);  // + both metas
    hipMemsetAsync(pooled, 0, (NG * NC + NG) * sizeof(float), stream);

    const int BT = 256;
    int bn = (N + BT - 1) / BT;
    int bp1 = (E + EPB - 1) / EPB;

    bucket_scatter_kernel<<<bp1, BT, 0, stream>>>(src, dst, E, nbk, bucket_cursor,
                                                  bucket_arr, bovf_meta, bovf);
    ell_build_kernel<<<nbk, BT, 0, stream>>>(bucket_arr, bucket_cursor, bovf_meta, bovf,
                                             ell, cnt, ovf_meta, ovf_dst, ovf_src, N);
    dinv_kernel<<<bn, BT, 0, stream>>>(cnt, dinv, N);

    layer1_kernel<<<(N + 3) / 4, BT, 0, stream>>>(x, W[0], dinv, g_a, N);

    // 5 mid layers: (b1,W2) .. (b5,W6), alternating g buffers
    gcn_layer_kernel<0><<<bn, BT, 0, stream>>>(cnt, ell, ovf_meta, ovf_dst, ovf_src, dinv, g_a, g_b, W[1], b[0], N);
    gcn_layer_kernel<0><<<bn, BT, 0, stream>>>(cnt, ell, ovf_meta, ovf_dst, ovf_src, dinv, g_b, g_a, W[2], b[1], N);
    gcn_layer_kernel<0><<<bn, BT, 0, stream>>>(cnt, ell, ovf_meta, ovf_dst, ovf_src, dinv, g_a, g_b, W[3], b[2], N);
    gcn_layer_kernel<0><<<bn, BT, 0, stream>>>(cnt, ell, ovf_meta, ovf_dst, ovf_src, dinv, g_b, g_a, W[4], b[3], N);
    gcn_layer_kernel<0><<<bn, BT, 0, stream>>>(cnt, ell, ovf_meta, ovf_dst, ovf_src, dinv, g_a, g_b, W[5], b[4], N);
    // layer 6 epilogue (b6), no next W
    gcn_layer_kernel<1><<<bn, BT, 0, stream>>>(cnt, ell, ovf_meta, ovf_dst, ovf_src, dinv, g_b, g_a, nullptr, b[5], N);
    // conv7 gather + Wf + bf + relu + pool
    pool_kernel<<<bn, BT, 0, stream>>>(cnt, ell, ovf_meta, ovf_dst, ovf_src, dinv, g_a, batch, W[6], b[6], pooled, gcnt, N);
    logsm_kernel<<<1, 64, 0, stream>>>(pooled, gcnt, out);
}

// Round 5
// 394.382 us; speedup vs baseline: 17.8150x; 1.2586x over previous
//
#include <hip/hip_runtime.h>
#include <hip/hip_bf16.h>
#include <math.h>

#define NF     128
#define HID    6
#define GP     8      // padded row stride for g (32B, two float4)
#define NC     10
#define NG     64
#define SLOTS  64     // ELL row capacity (deg ~ Poisson(32); P(deg>64) ~ 4e-7/node)
#define OVFCAP 8192

// bucket build params
#define BKT_SH    7
#define BKT_NODES 128
#define NBK_MAX   1024     // supports N <= 131072
#define EPB       4096     // edges per phase-1 block (256 thr x 16)
#define BCAP      5120     // per-bucket capacity (mean 4096, +16 sigma)
#define BOVFCAP   4096

__device__ __forceinline__ void add4(float4& a, const float4 b) {
    a.x += b.x; a.y += b.y; a.z += b.z; a.w += b.w;
}

// ---------------- phase 1: bin edges by dst>>7 with LDS ranking, semi-coalesced out ----------------
__global__ __launch_bounds__(256) void bucket_scatter_kernel(
        const int* __restrict__ src, const int* __restrict__ dst, int E, int nbk,
        int* __restrict__ bucket_cursor, unsigned int* __restrict__ bucket_arr,
        int* __restrict__ bovf_meta, int2* __restrict__ bovf) {
    __shared__ int cntL[NBK_MAX];
    __shared__ int offs[NBK_MAX];
    __shared__ int curL[NBK_MAX];
    __shared__ int gb[NBK_MAX];
    __shared__ int scanbuf[256];
    __shared__ unsigned int stage[EPB];
    __shared__ int gaddr[EPB];
    int tid = threadIdx.x;
    for (int k = tid; k < NBK_MAX; k += 256) cntL[k] = 0;
    __syncthreads();
    int e0 = blockIdx.x * EPB;
    int cnt_e = E - e0; if (cnt_e > EPB) cnt_e = EPB;
    int sreg[16], dreg[16];
    // pass A: count
#pragma unroll
    for (int k = 0; k < 16; ++k) {
        int e = e0 + k * 256 + tid;
        if (e < E) {
            int d = dst[e], s = src[e];
            sreg[k] = s; dreg[k] = d;
            atomicAdd(&cntL[d >> BKT_SH], 1);
        } else dreg[k] = -1;
    }
    __syncthreads();
    // exclusive block scan over NBK_MAX entries (4 per thread + Hillis-Steele on totals)
    int base = tid * 4;
    int c0 = cntL[base], c1 = cntL[base + 1], c2 = cntL[base + 2], c3 = cntL[base + 3];
    int tsum = c0 + c1 + c2 + c3;
    scanbuf[tid] = tsum;
    __syncthreads();
    for (int off = 1; off < 256; off <<= 1) {
        int v = (tid >= off) ? scanbuf[tid - off] : 0;
        __syncthreads();
        scanbuf[tid] += v;
        __syncthreads();
    }
    int ex = scanbuf[tid] - tsum;
    offs[base] = ex;
    offs[base + 1] = ex + c0;
    offs[base + 2] = ex + c0 + c1;
    offs[base + 3] = ex + c0 + c1 + c2;
    curL[base] = offs[base];
    curL[base + 1] = offs[base + 1];
    curL[base + 2] = offs[base + 2];
    curL[base + 3] = offs[base + 3];
    __syncthreads();
    // reserve global spans (one atomic per non-empty bucket per block)
    for (int b = tid; b < nbk; b += 256) {
        int c = cntL[b];
        if (c > 0) gb[b] = atomicAdd(&bucket_cursor[b], c);
    }
    __syncthreads();
    // pass B: rank into LDS staging
#pragma unroll
    for (int k = 0; k < 16; ++k) {
        int d = dreg[k];
        if (d < 0) continue;
        int s = sreg[k];
        int b = d >> BKT_SH;
        int pos = atomicAdd(&curL[b], 1);
        int rel = gb[b] + (pos - offs[b]);
        stage[pos] = (unsigned int)(d & (BKT_NODES - 1)) | ((unsigned int)s << BKT_SH);
        if (rel < BCAP) {
            gaddr[pos] = b * BCAP + rel;
        } else {  // bucket capacity overflow (~never)
            gaddr[pos] = -1;
            int p2 = atomicAdd(bovf_meta, 1);
            if (p2 < BOVFCAP) bovf[p2] = make_int2(d, s);
        }
    }
    __syncthreads();
    // copy out: consecutive j -> consecutive addresses within runs (semi-coalesced)
    for (int j = tid; j < cnt_e; j += 256) {
        int ga = gaddr[j];
        if (ga >= 0) bucket_arr[ga] = stage[j];
    }
}

// ---------------- phase 2: per-bucket ELL build in LDS, coalesced dump ----------------
__global__ __launch_bounds__(256) void ell_build_kernel(
        const unsigned int* __restrict__ bucket_arr, const int* __restrict__ bucket_cursor,
        const int* __restrict__ bovf_meta, const int2* __restrict__ bovf,
        int* __restrict__ ell, int* __restrict__ cnt,
        int* __restrict__ ovf_meta, int* __restrict__ ovf_dst, int* __restrict__ ovf_src,
        int N) {
    __shared__ int ell_s[BKT_NODES * SLOTS];   // 32KB
    __shared__ int cur[BKT_NODES];
    int b = blockIdx.x;
    int tid = threadIdx.x;
    if (tid < BKT_NODES) cur[tid] = 0;
    __syncthreads();
    int bc = bucket_cursor[b];
    if (bc > BCAP) bc = BCAP;
    const unsigned int* ba = bucket_arr + (size_t)b * BCAP;
    for (int j = tid; j < bc; j += 256) {
        unsigned int p = ba[j];
        int r = (int)(p & (BKT_NODES - 1));
        int s = (int)(p >> BKT_SH);
        int slot = atomicAdd(&cur[r], 1);
        if (slot < SLOTS) {
            ell_s[r * SLOTS + slot] = s;
        } else {  // node degree overflow (~never)
            int d = (b << BKT_SH) + r;
            int q = atomicAdd(ovf_meta, 1);
            if (q < OVFCAP) { ovf_dst[q] = d; ovf_src[q] = s; }
        }
    }
    // fold in bucket-capacity overflow edges (list is ~always empty)
    int m = *bovf_meta;
    if (m > BOVFCAP) m = BOVFCAP;
    for (int t = tid; t < m; t += 256) {
        int2 e = bovf[t];
        if ((e.x >> BKT_SH) == b) {
            int r = e.x & (BKT_NODES - 1);
            int slot = atomicAdd(&cur[r], 1);
            if (slot < SLOTS) {
                ell_s[r * SLOTS + slot] = e.y;
            } else {
                int q = atomicAdd(ovf_meta, 1);
                if (q < OVFCAP) { ovf_dst[q] = e.x; ovf_src[q] = e.y; }
            }
        }
    }
    __syncthreads();
    int nid0 = b << BKT_SH;
    int rows = N - nid0; if (rows > BKT_NODES) rows = BKT_NODES;
    if (rows <= 0) return;
    int4* eg = (int4*)(ell + (size_t)nid0 * SLOTS);
    const int4* es = (const int4*)ell_s;
    for (int k = tid; k < rows * (SLOTS / 4); k += 256) eg[k] = es[k];
    for (int r = tid; r < rows; r += 256) cnt[nid0 + r] = cur[r];
}

__global__ void dinv_kernel(const int* __restrict__ cnt, float* __restrict__ dinv, int N) {
    int i = blockIdx.x * blockDim.x + threadIdx.x;
    if (i < N) dinv[i] = rsqrtf((float)cnt[i] + 1.0f);  // +1 self loop
}

// ---------------- layer 1: g = dinv * (x @ W1), 8 lanes per node ----------------
// sub-lane s handles features [16s, 16s+16); sW layout [s][o][j], 100-float per-sub
// pad so the 8 subs hit disjoint bank quads (stride 100 dwords -> bank 4s).
__global__ __launch_bounds__(256) void layer1_kernel(const float* __restrict__ x,
                                                     const float* __restrict__ W,
                                                     const float* __restrict__ dinv,
                                                     float* __restrict__ g, int N) {
    __shared__ float sW[8 * 100];
    for (int idx = threadIdx.x; idx < NF * HID; idx += 256) {
        int s = idx / 96, r = idx % 96;
        int o = r / 16, j = r % 16;
        sW[s * 100 + o * 16 + j] = W[(s * 16 + j) * HID + o];
    }
    __syncthreads();
    int t = blockIdx.x * 256 + threadIdx.x;
    int i = t >> 3;
    int sub = t & 7;
    if (i >= N) return;
    const float4* xr = (const float4*)(x + (size_t)i * NF + sub * 16);
    float4 xv0 = xr[0], xv1 = xr[1], xv2 = xr[2], xv3 = xr[3];
    const float4* wr = (const float4*)(sW + sub * 100);
    float p[HID];
#pragma unroll
    for (int o = 0; o < HID; ++o) {
        float4 w0 = wr[o * 4 + 0], w1 = wr[o * 4 + 1], w2 = wr[o * 4 + 2], w3 = wr[o * 4 + 3];
        p[o] = xv0.x * w0.x + xv0.y * w0.y + xv0.z * w0.z + xv0.w * w0.w
             + xv1.x * w1.x + xv1.y * w1.y + xv1.z * w1.z + xv1.w * w1.w
             + xv2.x * w2.x + xv2.y * w2.y + xv2.z * w2.z + xv2.w * w2.w
             + xv3.x * w3.x + xv3.y * w3.y + xv3.z * w3.z + xv3.w * w3.w;
    }
#pragma unroll
    for (int m = 1; m < 8; m <<= 1) {
#pragma unroll
        for (int o = 0; o < HID; ++o) p[o] += __shfl_xor(p[o], m);
    }
    float dv = dinv[i];
    float4* g4 = (float4*)g;
    if (sub == 0) g4[2 * i]     = make_float4(dv * p[0], dv * p[1], dv * p[2], dv * p[3]);
    if (sub == 1) g4[2 * i + 1] = make_float4(dv * p[4], dv * p[5], 0.f, 0.f);
}

// ---------------- fused: gather + epilogue (+ next matmul), 8 lanes per node ----------------
// PREP=0: gout = dinv * (relu(dinv*(sum+self)+b) @ W)
// PREP=1: gout = dinv *  relu(dinv*(sum+self)+b)
template<int PREP>
__global__ __launch_bounds__(256) void gcn_layer8_kernel(
        const int* __restrict__ cnt, const int* __restrict__ ell,
        const int* __restrict__ ovf_meta, const int* __restrict__ ovf_dst,
        const int* __restrict__ ovf_src, const float* __restrict__ dinv,
        const float* __restrict__ gin, float* __restrict__ gout,
        const float* __restrict__ W, const float* __restrict__ b, int N) {
    int t = blockIdx.x * 256 + threadIdx.x;
    int i = t >> 3;
    int sub = t & 7;
    if (i >= N) return;
    int n = cnt[i];
    int ne = n < SLOTS ? n : SLOTS;
    const float4* g4 = (const float4*)gin;
    const int* er = ell + (size_t)i * SLOTS;
    float4 a0 = make_float4(0.f, 0.f, 0.f, 0.f), a1 = a0;
    for (int k = sub; k < ne; k += 8) {
        int s = er[k];
        add4(a0, g4[2 * s]); add4(a1, g4[2 * s + 1]);
    }
    // self-loop term, added exactly once across the subgroup
    if (sub == 0) add4(a0, g4[2 * i]);
    if (sub == 1) add4(a1, g4[2 * i + 1]);
    if (n > SLOTS && sub == 2) {  // ~never taken; correct fallback for deg>SLOTS
        int m = ovf_meta[0];
        m = m < OVFCAP ? m : OVFCAP;
        for (int tt = 0; tt < m; ++tt) {
            if (ovf_dst[tt] == i) {
                int s = ovf_src[tt];
                add4(a0, g4[2 * s]); add4(a1, g4[2 * s + 1]);
            }
        }
    }
    // butterfly over the 6 useful components (all 8 lanes end with the total)
    float s0 = a0.x, s1 = a0.y, s2 = a0.z, s3 = a0.w, s4 = a1.x, s5 = a1.y;
#pragma unroll
    for (int m = 1; m < 8; m <<= 1) {
        s0 += __shfl_xor(s0, m); s1 += __shfl_xor(s1, m); s2 += __shfl_xor(s2, m);
        s3 += __shfl_xor(s3, m); s4 += __shfl_xor(s4, m); s5 += __shfl_xor(s5, m);
    }
    float dv = dinv[i];
    float sum[HID] = { s0, s1, s2, s3, s4, s5 };
    float h[HID];
#pragma unroll
    for (int f = 0; f < HID; ++f) {
        float u = dv * sum[f] + b[f];
        h[f] = u > 0.0f ? u : 0.0f;
    }
    if (PREP) {
        if (sub == 0) ((float4*)gout)[2 * i]     = make_float4(dv * h[0], dv * h[1], dv * h[2], dv * h[3]);
        if (sub == 1) ((float4*)gout)[2 * i + 1] = make_float4(dv * h[4], dv * h[5], 0.f, 0.f);
    } else {
        float o[HID];
#pragma unroll
        for (int fo = 0; fo < HID; ++fo) {
            float s = 0.0f;
#pragma unroll
            for (int fi = 0; fi < HID; ++fi) s += h[fi] * W[fi * HID + fo];
            o[fo] = dv * s;
        }
        if (sub == 0) ((float4*)gout)[2 * i]     = make_float4(o[0], o[1], o[2], o[3]);
        if (sub == 1) ((float4*)gout)[2 * i + 1] = make_float4(o[4], o[5], 0.f, 0.f);
    }
}

// ---------------- pool: gather conv7 + Wf + relu + LDS mean-pool, 8 lanes per node ----------------
__global__ __launch_bounds__(256) void pool_kernel(
        const int* __restrict__ cnt, const int* __restrict__ ell,
        const int* __restrict__ ovf_meta, const int* __restrict__ ovf_dst,
        const int* __restrict__ ovf_src, const float* __restrict__ dinv,
        const float* __restrict__ gin, const int* __restrict__ batch,
        const float* __restrict__ Wf, const float* __restrict__ bf,
        float* __restrict__ pooled, float* __restrict__ gcnt, int N) {
    __shared__ float sp[NG * NC];
    __shared__ float sc[NG];
    __shared__ int srange[2];
    for (int k = threadIdx.x; k < NG * NC; k += 256) sp[k] = 0.0f;
    if (threadIdx.x < NG) sc[threadIdx.x] = 0.0f;
    int start = blockIdx.x * 32;           // 32 nodes per block (256 thr / 8)
    int endi = min(start + 32, N) - 1;
    if (threadIdx.x == 0) {
        srange[0] = batch[start];   // batch is sorted
        srange[1] = batch[endi];
    }
    __syncthreads();
    int t = blockIdx.x * 256 + threadIdx.x;
    int i = t >> 3;
    int sub = t & 7;
    if (i < N) {
        int n = cnt[i];
        int ne = n < SLOTS ? n : SLOTS;
        const float4* g4 = (const float4*)gin;
        const int* er = ell + (size_t)i * SLOTS;
        float4 a0 = make_float4(0.f, 0.f, 0.f, 0.f), a1 = a0;
        for (int k = sub; k < ne; k += 8) {
            int s = er[k];
            add4(a0, g4[2 * s]); add4(a1, g4[2 * s + 1]);
        }
        if (sub == 0) add4(a0, g4[2 * i]);
        if (sub == 1) add4(a1, g4[2 * i + 1]);
        if (n > SLOTS && sub == 2) {
            int m = ovf_meta[0];
            m = m < OVFCAP ? m : OVFCAP;
            for (int tt = 0; tt < m; ++tt) {
                if (ovf_dst[tt] == i) {
                    int s = ovf_src[tt];
                    add4(a0, g4[2 * s]); add4(a1, g4[2 * s + 1]);
                }
            }
        }
        float s0 = a0.x, s1 = a0.y, s2 = a0.z, s3 = a0.w, s4 = a1.x, s5 = a1.y;
#pragma unroll
        for (int m = 1; m < 8; m <<= 1) {
            s0 += __shfl_xor(s0, m); s1 += __shfl_xor(s1, m); s2 += __shfl_xor(s2, m);
            s3 += __shfl_xor(s3, m); s4 += __shfl_xor(s4, m); s5 += __shfl_xor(s5, m);
        }
        if (sub == 0) {
            float dv = dinv[i];
            float u[HID] = { dv * s0, dv * s1, dv * s2, dv * s3, dv * s4, dv * s5 };
            int bg = batch[i];
#pragma unroll
            for (int c = 0; c < NC; ++c) {
                float v = bf[c];
#pragma unroll
                for (int f = 0; f < HID; ++f) v += u[f] * Wf[f * NC + c];
                v = v > 0.0f ? v : 0.0f;
                atomicAdd(&sp[bg * NC + c], v);
            }
            atomicAdd(&sc[bg], 1.0f);
        }
    }
    __syncthreads();
    int bmin = srange[0], bmax = srange[1];
    int rows = bmax - bmin + 1;
    for (int k = threadIdx.x; k < rows * NC; k += 256) {
        int r = bmin + k / NC, c = k % NC;
        float v = sp[r * NC + c];
        if (v != 0.0f) atomicAdd(&pooled[r * NC + c], v);
    }
    for (int k = threadIdx.x; k < rows; k += 256) {
        float v = sc[bmin + k];
        if (v != 0.0f) atomicAdd(&gcnt[bmin + k], v);
    }
}

// ---------------- mean + log_softmax ----------------
__global__ void logsm_kernel(const float* __restrict__ pooled, const float* __restrict__ gcnt,
                             float* __restrict__ out) {
    int gidx = threadIdx.x;
    if (gidx >= NG) return;
    float c = gcnt[gidx];
    c = c > 1.0f ? c : 1.0f;
    float v[NC];
    float m = -1e30f;
#pragma unroll
    for (int k = 0; k < NC; ++k) {
        v[k] = pooled[gidx * NC + k] / c;
        m = v[k] > m ? v[k] : m;
    }
    float s = 0.0f;
#pragma unroll
    for (int k = 0; k < NC; ++k) s += expf(v[k] - m);
    float ls = logf(s);
#pragma unroll
    for (int k = 0; k < NC; ++k) out[gidx * NC + k] = v[k] - m - ls;
}

extern "C" void kernel_launch(void* const* d_in, const int* in_sizes, int n_in,
                              void* d_out, int out_size, void* d_ws, size_t ws_size,
                              hipStream_t stream) {
    const float* x     = (const float*)d_in[0];
    const int*   ei    = (const int*)d_in[1];
    const int*   batch = (const int*)d_in[2];
    const float* W[7];
    const float* b[7];
    for (int l = 0; l < 7; ++l) {
        W[l] = (const float*)d_in[3 + 2 * l];
        b[l] = (const float*)d_in[4 + 2 * l];
    }
    const int N = in_sizes[2];
    const int E = in_sizes[1] / 2;
    const int nbk = (N + BKT_NODES - 1) >> BKT_SH;
    const int* src = ei;
    const int* dst = ei + E;
    float* out = (float*)d_out;

    // workspace layout (16B-aligned blocks)
    char* wp = (char*)d_ws;
    int* bucket_cursor = (int*)wp;  wp += (size_t)NBK_MAX * 4;
    int* ovf_meta  = (int*)wp;      wp += 16;
    int* bovf_meta = (int*)wp;      wp += 16;   // metas contiguous with cursor -> one memset
    int* ovf_dst   = (int*)wp;      wp += OVFCAP * 4;
    int* ovf_src   = (int*)wp;      wp += OVFCAP * 4;
    int2* bovf     = (int2*)wp;     wp += (size_t)BOVFCAP * 8;
    int* cnt       = (int*)wp;      wp += (((size_t)N * 4 + 15) & ~15ull);
    float* dinv    = (float*)wp;    wp += (((size_t)N * 4 + 15) & ~15ull);
    float* g_a     = (float*)wp;    wp += (size_t)N * GP * 4;
    float* g_b     = (float*)wp;    wp += (size_t)N * GP * 4;
    float* pooled  = (float*)wp;    wp += NG * NC * 4;
    float* gcnt    = (float*)wp;    wp += (((size_t)NG * 4 + 15) & ~15ull);
    int* ell       = (int*)wp;      wp += (size_t)N * SLOTS * 4;
    unsigned int* bucket_arr = (unsigned int*)wp;  wp += (size_t)nbk * BCAP * 4;

    hipMemsetAsync(bucket_cursor, 0, (size_t)NBK_MAX * 4 + 32, stream);  // + both metas
    hipMemsetAsync(pooled, 0, (NG * NC + NG) * sizeof(float), stream);

    const int BT = 256;
    int bn = (N + BT - 1) / BT;
    int bn8 = ((size_t)N * 8 + BT - 1) / BT;
    int bp1 = (E + EPB - 1) / EPB;

    bucket_scatter_kernel<<<bp1, BT, 0, stream>>>(src, dst, E, nbk, bucket_cursor,
                                                  bucket_arr, bovf_meta, bovf);
    ell_build_kernel<<<nbk, BT, 0, stream>>>(bucket_arr, bucket_cursor, bovf_meta, bovf,
                                             ell, cnt, ovf_meta, ovf_dst, ovf_src, N);
    dinv_kernel<<<bn, BT, 0, stream>>>(cnt, dinv, N);

    layer1_kernel<<<bn8, BT, 0, stream>>>(x, W[0], dinv, g_a, N);

    // 5 mid layers: (b1,W2) .. (b5,W6), alternating g buffers
    gcn_layer8_kernel<0><<<bn8, BT, 0, stream>>>(cnt, ell, ovf_meta, ovf_dst, ovf_src, dinv, g_a, g_b, W[1], b[0], N);
    gcn_layer8_kernel<0><<<bn8, BT, 0, stream>>>(cnt, ell, ovf_meta, ovf_dst, ovf_src, dinv, g_b, g_a, W[2], b[1], N);
    gcn_layer8_kernel<0><<<bn8, BT, 0, stream>>>(cnt, ell, ovf_meta, ovf_dst, ovf_src, dinv, g_a, g_b, W[3], b[2], N);
    gcn_layer8_kernel<0><<<bn8, BT, 0, stream>>>(cnt, ell, ovf_meta, ovf_dst, ovf_src, dinv, g_b, g_a, W[4], b[3], N);
    gcn_layer8_kernel<0><<<bn8, BT, 0, stream>>>(cnt, ell, ovf_meta, ovf_dst, ovf_src, dinv, g_a, g_b, W[5], b[4], N);
    // layer 6 epilogue (b6), no next W
    gcn_layer8_kernel<1><<<bn8, BT, 0, stream>>>(cnt, ell, ovf_meta, ovf_dst, ovf_src, dinv, g_b, g_a, nullptr, b[5], N);
    // conv7 gather + Wf + bf + relu + pool
    pool_kernel<<<bn8, BT, 0, stream>>>(cnt, ell, ovf_meta, ovf_dst, ovf_src, dinv, g_a, batch, W[6], b[6], pooled, gcnt, N);
    logsm_kernel<<<1, 64, 0, stream>>>(pooled, gcnt, out);
}